// Round 4
// baseline (384.890 us; speedup 1.0000x reference)
//
#include <hip/hip_runtime.h>
#include <math.h>

#define BB   16
#define NN   2048
#define FIN  6
#define FOUT 128
#define KCH  6
#define KNN  40
#define NCLS 40

// ---------------------------------------------------------------------------
// Kernel A: per-row kNN. One WAVE per row, 4 rows/wave, 8 waves/block,
// 32 rows/block -> 1024 blocks. LDS ~53 KB -> 3 blocks/CU.
// Histogram: 128 bins over [0,4) packed 2x16-bit, widen/refine fallbacks.
// Emission: round-2-PROVEN collect(bin<=pivot) + 64-lane exact rank, ordered.
// ---------------------------------------------------------------------------
__global__ __launch_bounds__(512) void knn_kernel(const float* __restrict__ x,
                                                  int* __restrict__ topi,
                                                  float* __restrict__ topv,
                                                  float* __restrict__ dinv)
{
    __shared__ float          xs[FIN][NN];   // 48 KB
    __shared__ unsigned int   hist[8][64];   // 2 KB (2 bins per u32)
    __shared__ unsigned int   ck[8][64];     // 2 KB candidate keys
    __shared__ unsigned short ci[8][64];     // 1 KB candidate indices
    __shared__ unsigned int   ccnt[8];

    int bb   = blockIdx.x >> 6;              // 64 blocks per batch
    int i0   = (blockIdx.x & 63) * 32;       // first row of this block
    int t    = threadIdx.x;
    int lane = t & 63;
    int wv   = t >> 6;

    const float* xb = x + (size_t)bb * NN * FIN;
    for (int idx = t; idx < NN * FIN; idx += 512) {
        int j = idx / FIN, f = idx - j * FIN;
        xs[f][j] = xb[idx];
    }
    __syncthreads();                          // only block barrier

    for (int rr = 0; rr < 4; ++rr) {
        int i   = i0 + wv * 4 + rr;
        int row = bb * NN + i;

        float xi0 = xs[0][i], xi1 = xs[1][i], xi2 = xs[2][i];
        float xi3 = xs[3][i], xi4 = xs[4][i], xi5 = xs[5][i];

        // ---- distances: 32 per lane, registers ----
        float d[32];
#pragma unroll
        for (int u = 0; u < 32; ++u) {
            int j = u * 64 + lane;
            float t0 = xs[0][j] - xi0; float acc = t0 * t0;
            float t1 = xs[1][j] - xi1; acc = fmaf(t1, t1, acc);
            float t2 = xs[2][j] - xi2; acc = fmaf(t2, t2, acc);
            float t3 = xs[3][j] - xi3; acc = fmaf(t3, t3, acc);
            float t4 = xs[4][j] - xi4; acc = fmaf(t4, t4, acc);
            float t5 = xs[5][j] - xi5; acc = fmaf(t5, t5, acc);
            d[u] = acc;
        }

        // ---- histogram select: bin containing the 40th smallest ----
        float lo = 0.0f, invw = 32.0f;        // 128 bins of width 1/32 -> [0,4)
        int   base = 0, pivot = 127;

        for (int pass = 0; pass < 6; ++pass) {
            hist[wv][lane] = 0u;
#pragma unroll
            for (int u = 0; u < 32; ++u) {
                float dv = d[u];
                if (dv >= lo) {
                    int bin = (int)((dv - lo) * invw);
                    if (bin < 128)
                        atomicAdd(&hist[wv][bin >> 1], 1u << ((bin & 1) << 4));
                }
            }
            unsigned int h = hist[wv][lane];
            int b0 = (int)(h & 0xFFFFu), b1 = (int)(h >> 16);
            int s = b0 + b1;
            int incl = s;
#pragma unroll
            for (int off = 1; off < 64; off <<= 1) {
                int up = __shfl_up(incl, off, 64);
                if (lane >= off) incl += up;
            }
            int total = __shfl(incl, 63, 64);

            if (base + total < KNN) {         // range too small: widen
                base += total;
                lo   += 128.0f / invw;
                invw *= 0.5f;
                continue;
            }

            unsigned long long ball = __ballot(base + incl >= KNN);
            int pl = __ffsll(ball) - 1;
            int p_ = 0, cb_ = 0, cs_ = 0;
            if (lane == pl) {
                int cbefore = base + incl - s;
                if (cbefore + b0 >= KNN) { p_ = pl * 2;     cb_ = cbefore;      cs_ = cbefore + b0; }
                else                     { p_ = pl * 2 + 1; cb_ = cbefore + b0; cs_ = cbefore + b0 + b1; }
            }
            pivot    = __shfl(p_, pl, 64);
            int cumb = __shfl(cb_, pl, 64);
            int csel = __shfl(cs_, pl, 64);

            if (csel <= 64) break;            // all candidates fit one wave

            lo   = lo + (float)pivot / invw;  // refine inside crowded pivot bin
            invw *= 128.0f;
            base = cumb;
        }

        // ---- collect candidates (bin <= pivot; below-lo gives ib<=0) ----
        if (lane == 0) ccnt[wv] = 0u;
#pragma unroll
        for (int u = 0; u < 32; ++u) {
            int ib = (int)((d[u] - lo) * invw);   // negative for dv<lo
            if (ib <= pivot) {
                unsigned int slot = atomicAdd(&ccnt[wv], 1u);
                if (slot < 64u) {
                    ck[wv][slot] = __float_as_uint(d[u]);  // d>=0: uint order = float order
                    ci[wv][slot] = (unsigned short)(u * 64 + lane);
                }
            }
        }
        unsigned int c = ccnt[wv];
        if (c > 64u) c = 64u;

        unsigned int kk = (lane < (int)c) ? ck[wv][lane] : 0xFFFFFFFFu;
        int          id = (lane < (int)c) ? (int)ci[wv][lane] : -1;

        // ---- exact rank among <=64 candidates (round-2 proven) ----
        int rank = 0;
#pragma unroll
        for (int m = 0; m < 64; ++m) {
            unsigned int km = __shfl(kk, m, 64);
            rank += (km < kk || (km == kk && m < lane)) ? 1 : 0;
        }

        float ev = 0.0f;
        if (rank < KNN) {
            ev = expf(-__uint_as_float(kk));
            topv[(size_t)row * KNN + rank] = ev;
            topi[(size_t)row * KNN + rank] = id;
        }
        float ssum = ev;
#pragma unroll
        for (int off = 32; off; off >>= 1) ssum += __shfl_xor(ssum, off, 64);
        if (lane == 0) dinv[row] = 1.0f / sqrtf(ssum);
    }
}

// ---------------------------------------------------------------------------
// Kernel B: normalized edge weights  w[b,i,s] = dinv_i * A_is * dinv_{j_s}
// ---------------------------------------------------------------------------
__global__ void weight_kernel(const int* __restrict__ topi,
                              const float* __restrict__ topv,
                              const float* __restrict__ dinv,
                              float* __restrict__ wnrm)
{
    int idx = blockIdx.x * 256 + threadIdx.x;
    if (idx >= BB * NN * KNN) return;
    int row = idx / KNN;
    int b   = row >> 11;
    int j   = topi[idx];
    wnrm[idx] = topv[idx] * dinv[row] * dinv[b * NN + j];
}

// ---------------------------------------------------------------------------
// Kernel C: sparse Chebyshev step, thread = (row, feature).
//   xout[r,f] = scale * (xin[r,f] - sum_s w_s * xin[j_s,f]) - (xsub ? xsub[r,f] : 0)
// ---------------------------------------------------------------------------
__global__ __launch_bounds__(256) void cheb_apply(const float* __restrict__ xin,
                                                  const float* __restrict__ xsub,
                                                  float* __restrict__ xout,
                                                  const int* __restrict__ topi,
                                                  const float* __restrict__ wnrm,
                                                  float scale)
{
    int g = blockIdx.x * 256 + threadIdx.x;
    if (g >= BB * NN * FIN) return;
    int r = g / FIN, f = g - r * FIN;
    int b = r >> 11;
    const float* xbase = xin + (size_t)b * NN * FIN + f;
    const int*   ti = topi + (size_t)r * KNN;
    const float* tw = wnrm + (size_t)r * KNN;
    float a = xin[g];
#pragma unroll 8
    for (int s = 0; s < KNN; ++s)
        a = fmaf(-tw[s], xbase[(size_t)ti[s] * FIN], a);
    a *= scale;
    if (xsub) a -= xsub[g];
    xout[g] = a;
}

// ---------------------------------------------------------------------------
// Kernel D: out = relu( sum_k x_k @ W1[k] + b1 )  — block per row, 128 threads
// ---------------------------------------------------------------------------
__global__ __launch_bounds__(128) void chebout_kernel(const float* __restrict__ x,
                                                      const float* __restrict__ xks,
                                                      const float* __restrict__ W1,
                                                      const float* __restrict__ b1,
                                                      float* __restrict__ outb)
{
    int r = blockIdx.x;
    int t = threadIdx.x;
    __shared__ float xk[KCH][FIN];
    if (t < KCH * FIN) {
        int k = t / FIN, f = t % FIN;
        xk[k][f] = (k == 0) ? x[(size_t)r * FIN + f]
                            : xks[(size_t)(k - 1) * BB * NN * FIN + (size_t)r * FIN + f];
    }
    __syncthreads();
    float acc = b1[t];
#pragma unroll
    for (int k = 0; k < KCH; ++k)
#pragma unroll
        for (int f = 0; f < FIN; ++f)
            acc = fmaf(xk[k][f], W1[(k * FIN + f) * FOUT + t], acc);
    outb[(size_t)r * FOUT + t] = fmaxf(acc, 0.0f);
}

// ---------------------------------------------------------------------------
// Kernel E: Lout = L @ out  (sparse rows) — block per row, 128 threads
// ---------------------------------------------------------------------------
__global__ __launch_bounds__(128) void lout_kernel(const float* __restrict__ outb,
                                                   const int* __restrict__ topi,
                                                   const float* __restrict__ wnrm,
                                                   float* __restrict__ lout)
{
    int r = blockIdx.x;
    int t = threadIdx.x;
    int b = r >> 11;
    __shared__ int   si[KNN];
    __shared__ float sw[KNN];
    if (t < KNN) { si[t] = topi[(size_t)r * KNN + t]; sw[t] = wnrm[(size_t)r * KNN + t]; }
    __syncthreads();
    const float* ob = outb + (size_t)b * NN * FOUT;
    float acc = outb[(size_t)r * FOUT + t];
#pragma unroll 8
    for (int s = 0; s < KNN; ++s)
        acc -= sw[s] * ob[(size_t)si[s] * FOUT + t];
    lout[(size_t)r * FOUT + t] = acc;
}

// ---------------------------------------------------------------------------
// Kernel F: per-(batch, 16x16 tile of M) compute M = out^T Lout over n,
// square + block-reduce. 64-row transposed stages, float2 LDS reads.
// ---------------------------------------------------------------------------
__global__ __launch_bounds__(256) void msq_kernel(const float* __restrict__ outb,
                                                  const float* __restrict__ lout,
                                                  float* __restrict__ mpart)
{
    int bb    = blockIdx.y;
    int tile  = blockIdx.x;            // 0..63
    int tilef = tile & 7, tileg = tile >> 3;
    int t  = threadIdx.x;
    int tf = t & 15, tg = t >> 4;
    __shared__ float aT[16][66];       // [col][n-within-stage]
    __shared__ float bT[16][66];
    const float* ob = outb + (size_t)bb * NN * FOUT + tilef * 16;
    const float* lb = lout + (size_t)bb * NN * FOUT + tileg * 16;
    float acc = 0.f;
    int sc = t & 15, sr = t >> 4;
    for (int n0 = 0; n0 < NN; n0 += 64) {
#pragma unroll
        for (int c = 0; c < 4; ++c) {
            int nr = sr + 16 * c;
            aT[sc][nr] = ob[(size_t)(n0 + nr) * FOUT + sc];
            bT[sc][nr] = lb[(size_t)(n0 + nr) * FOUT + sc];
        }
        __syncthreads();
        const float2* a2 = (const float2*)aT[tf];
        const float2* b2 = (const float2*)bT[tg];
#pragma unroll
        for (int q = 0; q < 32; ++q) {
            float2 av = a2[q], bv = b2[q];
            acc = fmaf(av.x, bv.x, acc);
            acc = fmaf(av.y, bv.y, acc);
        }
        __syncthreads();
    }
    float s = acc * acc;
#pragma unroll
    for (int off = 32; off; off >>= 1) s += __shfl_down(s, off, 64);
    __shared__ float wsum[4];
    if ((t & 63) == 0) wsum[t >> 6] = s;
    __syncthreads();
    if (t == 0) mpart[bb * 64 + tile] = wsum[0] + wsum[1] + wsum[2] + wsum[3];
}

// ---------------------------------------------------------------------------
// Kernel G: partial max-pool over n chunks. grid (16 chunks, 16 batches)
// ---------------------------------------------------------------------------
__global__ __launch_bounds__(128) void pmax_kernel(const float* __restrict__ outb,
                                                   float* __restrict__ pmax)
{
    int c = blockIdx.x, b = blockIdx.y, t = threadIdx.x;
    const float* ob = outb + ((size_t)b * NN + (size_t)c * 128) * FOUT;
    float m = -3.0e38f;
#pragma unroll 4
    for (int n = 0; n < 128; ++n) m = fmaxf(m, ob[(size_t)n * FOUT + t]);
    pmax[((size_t)b * 16 + c) * FOUT + t] = m;
}

// ---------------------------------------------------------------------------
// Kernel H: finish max-pool + FC -> logits. grid 16 blocks, 128 threads
// ---------------------------------------------------------------------------
__global__ __launch_bounds__(128) void logits_kernel(const float* __restrict__ pmax,
                                                     const float* __restrict__ fcw,
                                                     const float* __restrict__ fcb,
                                                     float* __restrict__ dout)
{
    int b = blockIdx.x, t = threadIdx.x;
    __shared__ float pooled[FOUT];
    float m = pmax[((size_t)b * 16 + 0) * FOUT + t];
    for (int c = 1; c < 16; ++c) m = fmaxf(m, pmax[((size_t)b * 16 + c) * FOUT + t]);
    pooled[t] = m;
    __syncthreads();
    if (t < NCLS) {
        float acc = fcb[t];
        for (int f = 0; f < FOUT; ++f) acc = fmaf(pooled[f], fcw[f * NCLS + t], acc);
        dout[b * NCLS + t] = acc;
    }
}

// ---------------------------------------------------------------------------
// Kernel I: deterministic final reduction of 1024 reg partials
// ---------------------------------------------------------------------------
__global__ __launch_bounds__(256) void reg_kernel(const float* __restrict__ mpart,
                                                  float* __restrict__ dout)
{
    int t = threadIdx.x;
    float s = 0.f;
    for (int i = t; i < 1024; i += 256) s += mpart[i];
#pragma unroll
    for (int off = 32; off; off >>= 1) s += __shfl_down(s, off, 64);
    __shared__ float ws[4];
    if ((t & 63) == 0) ws[t >> 6] = s;
    __syncthreads();
    if (t == 0) dout[0] = ws[0] + ws[1] + ws[2] + ws[3];
}

// ---------------------------------------------------------------------------
extern "C" void kernel_launch(void* const* d_in, const int* in_sizes, int n_in,
                              void* d_out, int out_size, void* d_ws, size_t ws_size,
                              hipStream_t stream)
{
    const float* x   = (const float*)d_in[0];
    const float* W1  = (const float*)d_in[5];
    const float* b1  = (const float*)d_in[6];
    const float* fcw = (const float*)d_in[7];
    const float* fcb = (const float*)d_in[8];

    char* p = (char*)d_ws;
    auto alloc = [&](size_t bytes) { void* q = (void*)p; p += (bytes + 255) & ~(size_t)255; return q; };
    int*   topi  = (int*)  alloc((size_t)BB * NN * KNN * 4);
    float* topv  = (float*)alloc((size_t)BB * NN * KNN * 4);
    float* dinv  = (float*)alloc((size_t)BB * NN * 4);
    float* wnrm  = (float*)alloc((size_t)BB * NN * KNN * 4);
    float* xks   = (float*)alloc((size_t)5 * BB * NN * FIN * 4);   // x1..x5
    float* outb  = (float*)alloc((size_t)BB * NN * FOUT * 4);
    float* lout  = (float*)alloc((size_t)BB * NN * FOUT * 4);
    float* mpart = (float*)alloc(1024 * 4);
    float* pmax  = (float*)alloc((size_t)BB * 16 * FOUT * 4);

    const size_t ST = (size_t)BB * NN * FIN;   // per-Chebyshev-order stride

    knn_kernel<<<BB * 64, 512, 0, stream>>>(x, topi, topv, dinv);
    weight_kernel<<<(BB * NN * KNN + 255) / 256, 256, 0, stream>>>(topi, topv, dinv, wnrm);

    int cb = (BB * NN * FIN + 255) / 256;
    cheb_apply<<<cb, 256, 0, stream>>>(x,            nullptr,      xks + 0 * ST, topi, wnrm, 1.0f);
    cheb_apply<<<cb, 256, 0, stream>>>(xks + 0 * ST, x,            xks + 1 * ST, topi, wnrm, 2.0f);
    cheb_apply<<<cb, 256, 0, stream>>>(xks + 1 * ST, xks + 0 * ST, xks + 2 * ST, topi, wnrm, 2.0f);
    cheb_apply<<<cb, 256, 0, stream>>>(xks + 2 * ST, xks + 1 * ST, xks + 3 * ST, topi, wnrm, 2.0f);
    cheb_apply<<<cb, 256, 0, stream>>>(xks + 3 * ST, xks + 2 * ST, xks + 4 * ST, topi, wnrm, 2.0f);

    chebout_kernel<<<BB * NN, 128, 0, stream>>>(x, xks, W1, b1, outb);
    lout_kernel<<<BB * NN, 128, 0, stream>>>(outb, topi, wnrm, lout);
    msq_kernel<<<dim3(64, 16), 256, 0, stream>>>(outb, lout, mpart);
    pmax_kernel<<<dim3(16, 16), 128, 0, stream>>>(outb, pmax);
    logits_kernel<<<BB, 128, 0, stream>>>(pmax, fcw, fcb, (float*)d_out);
    reg_kernel<<<1, 256, 0, stream>>>(mpart, (float*)d_out + BB * NCLS);
}